// Round 15
// baseline (169.170 us; speedup 1.0000x reference)
//
#include <hip/hip_runtime.h>
#include <math.h>

#define DIMC 64
#define NE 512
#define HWSZ 4096              // 64*64
#define NPTS 131072
#define DECAYF 0.99f
#define OMD 0.01f
#define EPSF 1e-5f
#define MARGIN 1e-3f

// output offsets (floats) — out0 is [32,64,64,64] = 8388608 elements
#define O0 0
#define O1 8388608                 // diff scalar
#define O2 8388609                 // embed_ind [32,64,64]
#define O3 8519681                 // new_cluster_size [512]
#define O4 8520193                 // new_dictionary_avg [64,512]
#define O5 8552961                 // new_dictionary [64,512]
#define O6 8585729                 // mean_D scalar

// ws float-offset layout
#define WS_DIFF   0
#define WS_ESUM   64                       // [c][j] 64*512 f32 (reduced)
#define WS_COUNTS 32832                    // 512 f32 (contiguous after ESUM)
#define WS_DT     33344                    // [j][c] dictT f32, 32768
#define WS_NORM   66112                    // 512: -0.5*||d_j||^2
#define WS_DHI    66624                    // 512x64 bf16 (16384 floats)
#define WS_DLO    83008                    // 512x64 bf16
#define WS_BIDX   99392                    // NPTS ints (gap region)
#define WS_PART   246852                   // f32 partials: NBLK x 33280
#define PART_STRIDE 33280                  // 32768 esum + 512 counts
#define NBLK 256
#define WS_NEED_BYTES ((size_t)(WS_PART + (size_t)NBLK * PART_STRIDE) * 4)

typedef __attribute__((ext_vector_type(8))) short bf16x8;
typedef __attribute__((ext_vector_type(4))) float f32x4;

__device__ __forceinline__ unsigned bf16rne(float x) {
    unsigned u = __float_as_uint(x);
    return (u + 0x7FFFu + ((u >> 16) & 1u)) >> 16;
}

// -------- K1: dictT f32 + bf16 hi/lo + norms + zero accumulators --------
__global__ void k_prep(const float* __restrict__ dict, float* __restrict__ ws) {
    int j = blockIdx.x, c = threadIdx.x;
    float v = dict[c * NE + j];
    ws[WS_DT + j * DIMC + c] = v;
    unsigned h = bf16rne(v);
    float fh = __uint_as_float(h << 16);
    unsigned l = bf16rne(v - fh);
    ((unsigned short*)(ws + WS_DHI))[j * DIMC + c] = (unsigned short)h;
    ((unsigned short*)(ws + WS_DLO))[j * DIMC + c] = (unsigned short)l;
    ws[WS_ESUM + j * DIMC + c] = 0.f;      // reduce target (atomic-accumulated)
    if (c == 0) ws[WS_COUNTS + j] = 0.f;
    if (j == 0 && c == 0) ws[WS_DIFF] = 0.f;
    float s = v * v;
    #pragma unroll
    for (int off = 32; off > 0; off >>= 1) s += __shfl_down(s, off);
    if (c == 0) ws[WS_NORM + j] = -0.5f * s;
}

#define MFMA16(A, B, C) __builtin_amdgcn_mfma_f32_16x16x32_bf16(A, B, C, 0, 0, 0)

// -------- K2a: high-occupancy MFMA score + in-block rescan -> bidx -------
// 1024 blocks x 256 threads (4 waves); wave computes 32 points x 512 codes.
// 4 blocks/CU = 4 waves/SIMD. No f0 kept past staging.
__global__ __launch_bounds__(256, 4) void k_score(
        const float* __restrict__ x, float* __restrict__ ws) {
    __shared__ char stg[16384];            // 128 pts x 128 B (hi, then lo)
    __shared__ int bidxl[128];
    __shared__ int lflist[128];
    __shared__ int lcnt;

    const int tid  = threadIdx.x;
    const int lane = tid & 63;
    const int w    = tid >> 6;

    const int nb  = blockIdx.x * 128;
    const int b   = nb >> 12;
    const int hwb = nb & 4095;

    if (tid == 0) lcnt = 0;

    // ---- staged load: thread = (half h, point p); 32 c's each ----
    const int p = tid & 127, h = tid >> 7;
    const float* xp = x + (size_t)b * (DIMC * HWSZ) + (size_t)(32 * h) * HWSZ
                        + hwb + p;
    unsigned hiu[16], lou[16];
    #pragma unroll
    for (int i = 0; i < 16; ++i) {
        float v0 = xp[(2 * i) * HWSZ];
        float v1 = xp[(2 * i + 1) * HWSZ];
        unsigned h0 = bf16rne(v0), h1 = bf16rne(v1);
        float r0 = v0 - __uint_as_float(h0 << 16);
        float r1 = v1 - __uint_as_float(h1 << 16);
        hiu[i] = h0 | (h1 << 16);
        lou[i] = bf16rne(r0) | (bf16rne(r1) << 16);
    }
    const int swz = p & 7;
    #pragma unroll
    for (int k = 0; k < 4; ++k) {
        uint4 u = {hiu[4 * k], hiu[4 * k + 1], hiu[4 * k + 2], hiu[4 * k + 3]};
        *(uint4*)(stg + p * 128 + (((4 * h + k) ^ swz) << 4)) = u;
    }
    __syncthreads();

    // ---- A-fragments hi (row = w*32 + pt*16 + (lane&15)) ----
    bf16x8 ahi[2][2], alo[2][2];
    #pragma unroll
    for (int pt = 0; pt < 2; ++pt) {
        const int row = (w << 5) + (pt << 4) + (lane & 15);
        #pragma unroll
        for (int kk = 0; kk < 2; ++kk) {
            const int ch = (lane >> 4) + (kk << 2);
            ahi[pt][kk] = __builtin_bit_cast(bf16x8,
                *(const uint4*)(stg + row * 128 + ((ch ^ (row & 7)) << 4)));
        }
    }
    __syncthreads();

    // ---- stage lo (same buffer), read lo frags ----
    #pragma unroll
    for (int k = 0; k < 4; ++k) {
        uint4 u = {lou[4 * k], lou[4 * k + 1], lou[4 * k + 2], lou[4 * k + 3]};
        *(uint4*)(stg + p * 128 + (((4 * h + k) ^ swz) << 4)) = u;
    }
    __syncthreads();
    #pragma unroll
    for (int pt = 0; pt < 2; ++pt) {
        const int row = (w << 5) + (pt << 4) + (lane & 15);
        #pragma unroll
        for (int kk = 0; kk < 2; ++kk) {
            const int ch = (lane >> 4) + (kk << 2);
            alo[pt][kk] = __builtin_bit_cast(bf16x8,
                *(const uint4*)(stg + row * 128 + ((ch ^ (row & 7)) << 4)));
        }
    }
    __syncthreads();   // stg dead (bidxl is separate; just order discipline)

    // ---- MFMA sweep over 32 code-tiles ----
    const uint4* dh4 = (const uint4*)(ws + WS_DHI);
    const uint4* dl4 = (const uint4*)(ws + WS_DLO);
    const float* npl = ws + WS_NORM + (lane & 15);
    const int bl = ((lane & 15) << 3) + (lane >> 4);

    float best[2][4], sec[2][4];
    int   idx[2][4];
    #pragma unroll
    for (int pt = 0; pt < 2; ++pt)
        #pragma unroll
        for (int r = 0; r < 4; ++r) {
            best[pt][r] = -3.4e38f; sec[pt][r] = -3.4e38f; idx[pt][r] = 0;
        }

    #pragma unroll 2
    for (int jt = 0; jt < 32; ++jt) {
        uint4 uh0 = dh4[(jt << 7) + bl];
        uint4 uh1 = dh4[(jt << 7) + bl + 4];
        uint4 ul0 = dl4[(jt << 7) + bl];
        uint4 ul1 = dl4[(jt << 7) + bl + 4];
        float nrm = npl[jt << 4];
        bf16x8 bh0 = __builtin_bit_cast(bf16x8, uh0);
        bf16x8 bh1 = __builtin_bit_cast(bf16x8, uh1);
        bf16x8 bl0 = __builtin_bit_cast(bf16x8, ul0);
        bf16x8 bl1 = __builtin_bit_cast(bf16x8, ul1);
        const int jc = (jt << 4) + (lane & 15);
        #pragma unroll
        for (int pt = 0; pt < 2; ++pt) {
            f32x4 acc = {0.f, 0.f, 0.f, 0.f};
            acc = MFMA16(ahi[pt][0], bh0, acc);
            acc = MFMA16(ahi[pt][1], bh1, acc);
            acc = MFMA16(ahi[pt][0], bl0, acc);
            acc = MFMA16(ahi[pt][1], bl1, acc);
            acc = MFMA16(alo[pt][0], bh0, acc);
            acc = MFMA16(alo[pt][1], bh1, acc);
            acc = MFMA16(alo[pt][0], bl0, acc);
            acc = MFMA16(alo[pt][1], bl1, acc);
            #pragma unroll
            for (int r = 0; r < 4; ++r) {
                float s = acc[r] + nrm;
                bool gt = s > best[pt][r];
                float ns = gt ? best[pt][r] : (s > sec[pt][r] ? s : sec[pt][r]);
                best[pt][r] = gt ? s : best[pt][r];
                idx[pt][r]  = gt ? jc : idx[pt][r];
                sec[pt][r]  = ns;
            }
        }
    }

    // ---- argmax reduce across 16-lane code groups ----
    #pragma unroll
    for (int off = 8; off > 0; off >>= 1) {
        #pragma unroll
        for (int pt = 0; pt < 2; ++pt)
            #pragma unroll
            for (int r = 0; r < 4; ++r) {
                float ob = __shfl_xor(best[pt][r], off, 16);
                float os = __shfl_xor(sec[pt][r], off, 16);
                int   oi = __shfl_xor(idx[pt][r], off, 16);
                bool take = (ob > best[pt][r]) ||
                            (ob == best[pt][r] && oi < idx[pt][r]);
                float nsec = fmaxf(fminf(ob, best[pt][r]),
                                   fmaxf(os, sec[pt][r]));
                best[pt][r] = take ? ob : best[pt][r];
                idx[pt][r]  = take ? oi : idx[pt][r];
                sec[pt][r]  = nsec;
            }
    }
    if ((lane & 15) == 0) {
        const int g = lane >> 4;
        #pragma unroll
        for (int pt = 0; pt < 2; ++pt)
            #pragma unroll
            for (int r = 0; r < 4; ++r) {
                int pp = (w << 5) + (pt << 4) + (g << 2) + r;
                int flag = (best[pt][r] - sec[pt][r] < MARGIN) ? 65536 : 0;
                bidxl[pp] = idx[pt][r] | flag;
            }
    }
    __syncthreads();

    // ---- build flagged list ----
    if (tid < 128) {
        int e = bidxl[tid];
        if (e & 65536) {
            int pos = atomicAdd(&lcnt, 1);
            lflist[pos] = tid;
        }
    }
    __syncthreads();

    // ---- in-block exact rescan, one wave per flagged point --------------
    const float* dptr = ws + WS_DT;
    {
        const int nf = lcnt;
        for (int fi = w; fi < nf; fi += 4) {
            const int pp = lflist[fi];
            const float xv = x[(size_t)b * (DIMC * HWSZ)
                               + (size_t)lane * HWSZ + hwb + pp];
            float bb = -3.4e38f; int bj = 0;
            #pragma unroll 2
            for (int s = 0; s < 8; ++s) {
                const int j = (lane << 3) + s;
                const float4* row = (const float4*)(dptr + (size_t)j * DIMC);
                float a0 = 0.f, a1 = 0.f, a2 = 0.f, a3 = 0.f;
                #pragma unroll
                for (int c4 = 0; c4 < 16; ++c4) {
                    float4 r4 = row[c4];
                    a0 = fmaf(r4.x, __shfl(xv, 4 * c4 + 0), a0);
                    a1 = fmaf(r4.y, __shfl(xv, 4 * c4 + 1), a1);
                    a2 = fmaf(r4.z, __shfl(xv, 4 * c4 + 2), a2);
                    a3 = fmaf(r4.w, __shfl(xv, 4 * c4 + 3), a3);
                }
                float sc = ((a0 + a1) + (a2 + a3)) + ws[WS_NORM + j];
                if (sc > bb) { bb = sc; bj = j; }
            }
            #pragma unroll
            for (int off = 1; off < 64; off <<= 1) {
                float ob = __shfl_xor(bb, off);
                int   oi = __shfl_xor(bj, off);
                bool take = (ob > bb) || (ob == bb && oi < bj);
                bb = take ? ob : bb;
                bj = take ? oi : bj;
            }
            if (lane == 0) bidxl[pp] = bj;
        }
    }
    __syncthreads();

    if (tid < 128) ((int*)ws)[WS_BIDX + nb + tid] = bidxl[tid] & 511;
}

// -------- K2b: gather/quantize/stats; all global stores post-barrier -----
__global__ __launch_bounds__(512, 1) void k_emit(
        const float* __restrict__ x, float* __restrict__ ws,
        float* __restrict__ out, int use_part) {
    extern __shared__ float lds[];
    float* esum  = lds;                 // 32768: esum_t [c][j]
    int*   lhist = (int*)(lds + 32768); // 512
    float* lred  = lds + 33280;         // 8

    const int tid = threadIdx.x;
    {
        float4 z = {0.f, 0.f, 0.f, 0.f};
        float4* e4 = (float4*)esum;
        #pragma unroll
        for (int k = 0; k < 16; ++k) e4[tid + 512 * k] = z;
        lhist[tid] = 0;
    }
    __syncthreads();

    const int n0 = blockIdx.x * 512 + tid;
    const int b = n0 >> 12, hw0 = n0 & 4095;
    const float* xp = x + (size_t)b * (DIMC * HWSZ) + hw0;
    float f0[DIMC];
    #pragma unroll
    for (int c = 0; c < DIMC; ++c) f0[c] = xp[c * HWSZ];

    const int bi0 = ((const int*)ws)[WS_BIDX + n0];
    atomicAdd(&lhist[bi0], 1);

    // esum scatter (LDS, banks spread by bidx)
    #pragma unroll
    for (int c = 0; c < DIMC; ++c) atomicAdd(&esum[c * NE + bi0], f0[c]);

    // q gather + diff partials (no stores yet)
    const float* dptr = ws + WS_DT;
    float ssum = 0.f;
    const float4* q40 = (const float4*)(dptr + (size_t)bi0 * DIMC);
    #pragma unroll
    for (int c4 = 0; c4 < 16; ++c4) {
        float4 qa = q40[c4];
        const int cb = 4 * c4;
        float d;
        d = qa.x - f0[cb + 0]; ssum = fmaf(d, d, ssum);
        d = qa.y - f0[cb + 1]; ssum = fmaf(d, d, ssum);
        d = qa.z - f0[cb + 2]; ssum = fmaf(d, d, ssum);
        d = qa.w - f0[cb + 3]; ssum = fmaf(d, d, ssum);
    }
    #pragma unroll
    for (int off = 32; off > 0; off >>= 1) ssum += __shfl_down(ssum, off);
    if ((tid & 63) == 0) lred[tid >> 6] = ssum;
    __syncthreads();

    // ---- post-barrier: all global stores (no trailing barrier/drain) ----
    if (use_part) {
        float* part = ws + WS_PART + (size_t)blockIdx.x * PART_STRIDE;
        float4* p4 = (float4*)part;
        const float4* e4 = (const float4*)esum;
        #pragma unroll
        for (int k = 0; k < 16; ++k) p4[tid + 512 * k] = e4[tid + 512 * k];
        part[32768 + tid] = (float)lhist[tid];
    } else {
        #pragma unroll
        for (int k = 0; k < 64; ++k)
            atomicAdd(&ws[WS_ESUM + tid + 512 * k], esum[tid + 512 * k]);
        atomicAdd(&ws[WS_COUNTS + tid], (float)lhist[tid]);
    }

    out[O2 + n0] = (float)bi0;
    float* o0 = out + O0 + (size_t)b * (DIMC * HWSZ) + hw0;
    #pragma unroll
    for (int c4 = 0; c4 < 16; ++c4) {
        float4 qa = q40[c4];        // re-gather (L2-hot)
        const int cb = 4 * c4;
        o0[(cb + 0) * HWSZ] = qa.x;
        o0[(cb + 1) * HWSZ] = qa.y;
        o0[(cb + 2) * HWSZ] = qa.z;
        o0[(cb + 3) * HWSZ] = qa.w;
    }

    if (tid == 0) {
        float t = 0.f;
        #pragma unroll
        for (int w2 = 0; w2 < 8; ++w2) t += lred[w2];
        atomicAdd(ws + WS_DIFF, t);
    }
}

// -------- K2d: parallel partial reduce (260 blocks, spread atomics) ------
__global__ void k_reduce(float* __restrict__ ws) {
    const int tid = threadIdx.x;
    const int gid = (blockIdx.x % 65) * 128 + tid;     // [0, 8320) float4 pos
    const int slice = blockIdx.x / 65;                  // [0, 4)
    const float4* src = (const float4*)(ws + WS_PART);
    float4 acc = {0.f, 0.f, 0.f, 0.f};
    const int p0 = slice * 64;
    #pragma unroll 4
    for (int p = p0; p < p0 + 64; ++p) {
        float4 v = src[(size_t)p * (PART_STRIDE / 4) + gid];
        acc.x += v.x; acc.y += v.y; acc.z += v.z; acc.w += v.w;
    }
    float* dst = ws + WS_ESUM + gid * 4;                // COUNTS follows ESUM
    atomicAdd(dst + 0, acc.x);
    atomicAdd(dst + 1, acc.y);
    atomicAdd(dst + 2, acc.z);
    atomicAdd(dst + 3, acc.w);
}

// -------- K3: finalize EMA buffers / outputs --------
__global__ void k_final(const float* __restrict__ ws,
                        const float* __restrict__ cluster_size,
                        const float* __restrict__ davg,
                        float* __restrict__ out) {
    __shared__ float red[16];
    __shared__ float nsh;
    const int j = threadIdx.x;

    float cnt = ws[WS_COUNTS + j];
    float ncs = DECAYF * cluster_size[j] + OMD * cnt;
    out[O3 + j] = ncs;

    float v = ncs;
    #pragma unroll
    for (int off = 32; off > 0; off >>= 1) v += __shfl_down(v, off);
    if ((j & 63) == 0) red[j >> 6] = v;
    __syncthreads();
    if (j == 0) {
        float t = 0.f;
        #pragma unroll
        for (int w = 0; w < 8; ++w) t += red[w];
        nsh = t;
    }
    __syncthreads();
    const float n = nsh;
    const float csj = (ncs + EPSF) / (n + NE * EPSF) * n;

    float asum = 0.f;
    #pragma unroll
    for (int c = 0; c < DIMC; ++c) {
        float es = ws[WS_ESUM + c * NE + j];
        float da = davg[c * NE + j];
        float nda = DECAYF * da + OMD * es;
        out[O4 + c * NE + j] = nda;
        float nd = nda / csj;
        out[O5 + c * NE + j] = nd;
        asum += fabsf(nd);
    }

    __syncthreads();
    #pragma unroll
    for (int off = 32; off > 0; off >>= 1) asum += __shfl_down(asum, off);
    if ((j & 63) == 0) red[j >> 6] = asum;
    __syncthreads();
    if (j == 0) {
        float t = 0.f;
        #pragma unroll
        for (int w = 0; w < 8; ++w) t += red[w];
        out[O6] = t / 32768.0f;
        out[O1] = ws[WS_DIFF] / 8388608.0f;
    }
}

extern "C" void kernel_launch(void* const* d_in, const int* in_sizes, int n_in,
                              void* d_out, int out_size, void* d_ws, size_t ws_size,
                              hipStream_t stream) {
    const float* x    = (const float*)d_in[0];
    const float* dict = (const float*)d_in[1];
    const float* csz  = (const float*)d_in[2];
    const float* davg = (const float*)d_in[3];
    float* out = (float*)d_out;
    float* ws  = (float*)d_ws;

    const int use_part = (ws_size >= WS_NEED_BYTES) ? 1 : 0;

    k_prep<<<512, 64, 0, stream>>>(dict, ws);

    k_score<<<1024, 256, 0, stream>>>(x, ws);

    const int emit_lds = 33288 * 4;
    hipFuncSetAttribute((const void*)k_emit,
                        hipFuncAttributeMaxDynamicSharedMemorySize, emit_lds);
    k_emit<<<NBLK, 512, emit_lds, stream>>>(x, ws, out, use_part);

    if (use_part) k_reduce<<<260, 128, 0, stream>>>(ws);

    k_final<<<1, 512, 0, stream>>>(ws, csz, davg, out);
}

// Round 17
// 147.841 us; speedup vs baseline: 1.1443x; 1.1443x over previous
//
#include <hip/hip_runtime.h>
#include <math.h>

#define DIMC 64
#define NE 512
#define HWSZ 4096              // 64*64
#define NPTS 131072
#define DECAYF 0.99f
#define OMD 0.01f
#define EPSF 1e-5f
#define MARGIN 1e-3f

// output offsets (floats) — out0 is [32,64,64,64] = 8388608 elements
#define O0 0
#define O1 8388608                 // diff scalar
#define O2 8388609                 // embed_ind [32,64,64]
#define O3 8519681                 // new_cluster_size [512]
#define O4 8520193                 // new_dictionary_avg [64,512]
#define O5 8552961                 // new_dictionary [64,512]
#define O6 8585729                 // mean_D scalar

// ws float-offset layout
#define WS_DIFF   0
#define WS_ESUM   64                       // [c][j] 64*512 f32 (reduced)
#define WS_COUNTS 32832                    // 512 f32 (contiguous after ESUM)
#define WS_DT     33344                    // [j][c] dictT f32, 32768
#define WS_NORM   66112                    // 512: -0.5*||d_j||^2
#define WS_DHI    66624                    // 512x64 bf16 (16384 floats)
#define WS_DLO    83008                    // 512x64 bf16
#define WS_BIDX   99392                    // NPTS ints (gap region)
#define WS_PART   246852                   // f32 partials: NBLK x 33280
#define PART_STRIDE 33280                  // 32768 esum + 512 counts
#define NBLK 256
#define WS_NEED_BYTES ((size_t)(WS_PART + (size_t)NBLK * PART_STRIDE) * 4)

typedef __attribute__((ext_vector_type(8))) short bf16x8;
typedef __attribute__((ext_vector_type(4))) float f32x4;

__device__ __forceinline__ unsigned bf16rne(float x) {
    unsigned u = __float_as_uint(x);
    return (u + 0x7FFFu + ((u >> 16) & 1u)) >> 16;
}

// -------- K1: dictT f32 + bf16 hi/lo + norms + zero accumulators --------
__global__ void k_prep(const float* __restrict__ dict, float* __restrict__ ws) {
    int j = blockIdx.x, c = threadIdx.x;
    float v = dict[c * NE + j];
    ws[WS_DT + j * DIMC + c] = v;
    unsigned h = bf16rne(v);
    float fh = __uint_as_float(h << 16);
    unsigned l = bf16rne(v - fh);
    ((unsigned short*)(ws + WS_DHI))[j * DIMC + c] = (unsigned short)h;
    ((unsigned short*)(ws + WS_DLO))[j * DIMC + c] = (unsigned short)l;
    ws[WS_ESUM + j * DIMC + c] = 0.f;      // reduce target (atomic-accumulated)
    if (c == 0) ws[WS_COUNTS + j] = 0.f;
    if (j == 0 && c == 0) ws[WS_DIFF] = 0.f;
    float s = v * v;
    #pragma unroll
    for (int off = 32; off > 0; off >>= 1) s += __shfl_down(s, off);
    if (c == 0) ws[WS_NORM + j] = -0.5f * s;
}

#define MFMA16(A, B, C) __builtin_amdgcn_mfma_f32_16x16x32_bf16(A, B, C, 0, 0, 0)

// -------- K2a: MFMA score, dict in LDS via TWO-PASS staging -> bidx -------
// 512 blocks x 512 threads (8 waves); wave computes 32 points x 512 codes.
// Dict bf16 hi/lo staged 256 codes at a time (64 KB), swept, restaged.
__global__ __launch_bounds__(512, 1) void k_score(
        const float* __restrict__ x, float* __restrict__ ws) {
    extern __shared__ float lds[];
    uint4* ldh   = (uint4*)lds;            // [2048] pass dict hi (32 KB)
    uint4* ldl   = (uint4*)lds + 2048;     // [2048] pass dict lo (32 KB)
    float* lnrm  = lds + 16384;            // 512
    char*  stgB  = (char*)(lds + 16896);   // 32 KB x staging (hi then lo)
    int*   bidxl = (int*)(lds + 16896);    // overlay after frag loads: 256
    int*   lflist= (int*)(lds + 16896) + 256;
    int*   lcnt  = (int*)(lds + 16896) + 512;

    const int tid  = threadIdx.x;
    const int lane = tid & 63;
    const int w    = tid >> 6;

    const int nb  = blockIdx.x * 256;
    const int b   = nb >> 12;
    const int hwb = nb & 4095;

    // ---- stage dict pass 0 (codes 0..255, hi+lo) + norms ----
    {
        const uint4* gdh = (const uint4*)(ws + WS_DHI);
        const uint4* gdl = (const uint4*)(ws + WS_DLO);
        #pragma unroll
        for (int k = 0; k < 4; ++k) {
            const int i = k * 512 + tid;           // [0, 2048)
            const int cl = i >> 3, ch = i & 7;     // code_local, chunk
            const int dp = cl * 8 + (ch ^ (cl & 7));
            ldh[dp] = gdh[i];
            ldl[dp] = gdl[i];
        }
        lnrm[tid] = ws[WS_NORM + tid];
    }

    // ---- staged x load: thread = (half h, point p); 32 c's each ----
    const int p = tid & 255, h = tid >> 8;
    const float* xp = x + (size_t)b * (DIMC * HWSZ) + (size_t)(32 * h) * HWSZ
                        + hwb + p;
    unsigned hiu[16], lou[16];
    #pragma unroll
    for (int i = 0; i < 16; ++i) {
        float v0 = xp[(2 * i) * HWSZ];
        float v1 = xp[(2 * i + 1) * HWSZ];
        unsigned h0 = bf16rne(v0), h1 = bf16rne(v1);
        float r0 = v0 - __uint_as_float(h0 << 16);
        float r1 = v1 - __uint_as_float(h1 << 16);
        hiu[i] = h0 | (h1 << 16);
        lou[i] = bf16rne(r0) | (bf16rne(r1) << 16);
    }
    const int swz = p & 7;
    #pragma unroll
    for (int k = 0; k < 4; ++k) {
        uint4 u = {hiu[4 * k], hiu[4 * k + 1], hiu[4 * k + 2], hiu[4 * k + 3]};
        *(uint4*)(stgB + p * 128 + (((4 * h + k) ^ swz) << 4)) = u;
    }
    __syncthreads();

    // ---- A-fragments hi (row = w*32 + pt*16 + (lane&15)) ----
    bf16x8 ahi[2][2], alo[2][2];
    #pragma unroll
    for (int pt = 0; pt < 2; ++pt) {
        const int row = (w << 5) + (pt << 4) + (lane & 15);
        #pragma unroll
        for (int kk = 0; kk < 2; ++kk) {
            const int ch = (lane >> 4) + (kk << 2);
            ahi[pt][kk] = __builtin_bit_cast(bf16x8,
                *(const uint4*)(stgB + row * 128 + ((ch ^ (row & 7)) << 4)));
        }
    }
    __syncthreads();

    // ---- stage x lo (same buffer), read lo frags ----
    #pragma unroll
    for (int k = 0; k < 4; ++k) {
        uint4 u = {lou[4 * k], lou[4 * k + 1], lou[4 * k + 2], lou[4 * k + 3]};
        *(uint4*)(stgB + p * 128 + (((4 * h + k) ^ swz) << 4)) = u;
    }
    __syncthreads();
    #pragma unroll
    for (int pt = 0; pt < 2; ++pt) {
        const int row = (w << 5) + (pt << 4) + (lane & 15);
        #pragma unroll
        for (int kk = 0; kk < 2; ++kk) {
            const int ch = (lane >> 4) + (kk << 2);
            alo[pt][kk] = __builtin_bit_cast(bf16x8,
                *(const uint4*)(stgB + row * 128 + ((ch ^ (row & 7)) << 4)));
        }
    }
    if (tid == 0) lcnt[0] = 0;
    __syncthreads();   // staging dead -> stgB reusable as bidxl/lflist

    // ---- MFMA sweep: 2 passes x 16 code-tiles; B from LDS ----
    const int col = lane & 15, g = lane >> 4;
    const int cswz = col & 7;
    const float* nl = lnrm + col;

    float best[2][4], sec[2][4];
    int   idx[2][4];
    #pragma unroll
    for (int pt = 0; pt < 2; ++pt)
        #pragma unroll
        for (int r = 0; r < 4; ++r) {
            best[pt][r] = -3.4e38f; sec[pt][r] = -3.4e38f; idx[pt][r] = 0;
        }

    for (int pass = 0; pass < 2; ++pass) {
        if (pass) {
            __syncthreads();   // all waves done with pass-0 dict
            const uint4* gdh = (const uint4*)(ws + WS_DHI) + 2048;
            const uint4* gdl = (const uint4*)(ws + WS_DLO) + 2048;
            #pragma unroll
            for (int k = 0; k < 4; ++k) {
                const int i = k * 512 + tid;
                const int cl = i >> 3, ch = i & 7;
                const int dp = cl * 8 + (ch ^ (cl & 7));
                ldh[dp] = gdh[i];
                ldl[dp] = gdl[i];
            }
            __syncthreads();
        }

        #pragma unroll 2
        for (int tt = 0; tt < 16; ++tt) {
            const int base = (tt << 7) + (col << 3);
            uint4 uh0 = ldh[base + (g ^ cswz)];
            uint4 uh1 = ldh[base + ((g + 4) ^ cswz)];
            uint4 ul0 = ldl[base + (g ^ cswz)];
            uint4 ul1 = ldl[base + ((g + 4) ^ cswz)];
            const int jt = (pass << 4) + tt;
            float nrm = nl[jt << 4];
            bf16x8 bh0 = __builtin_bit_cast(bf16x8, uh0);
            bf16x8 bh1 = __builtin_bit_cast(bf16x8, uh1);
            bf16x8 bl0 = __builtin_bit_cast(bf16x8, ul0);
            bf16x8 bl1 = __builtin_bit_cast(bf16x8, ul1);
            const int jc = (jt << 4) + col;
            #pragma unroll
            for (int pt = 0; pt < 2; ++pt) {
                f32x4 acc = {0.f, 0.f, 0.f, 0.f};
                acc = MFMA16(ahi[pt][0], bh0, acc);
                acc = MFMA16(ahi[pt][1], bh1, acc);
                acc = MFMA16(ahi[pt][0], bl0, acc);
                acc = MFMA16(ahi[pt][1], bl1, acc);
                acc = MFMA16(alo[pt][0], bh0, acc);
                acc = MFMA16(alo[pt][1], bh1, acc);
                acc = MFMA16(alo[pt][0], bl0, acc);
                acc = MFMA16(alo[pt][1], bl1, acc);
                #pragma unroll
                for (int r = 0; r < 4; ++r) {
                    float s = acc[r] + nrm;
                    bool gt = s > best[pt][r];
                    float ns = gt ? best[pt][r] : (s > sec[pt][r] ? s : sec[pt][r]);
                    best[pt][r] = gt ? s : best[pt][r];
                    idx[pt][r]  = gt ? jc : idx[pt][r];
                    sec[pt][r]  = ns;
                }
            }
        }
    }

    // ---- argmax reduce across 16-lane code groups ----
    #pragma unroll
    for (int off = 8; off > 0; off >>= 1) {
        #pragma unroll
        for (int pt = 0; pt < 2; ++pt)
            #pragma unroll
            for (int r = 0; r < 4; ++r) {
                float ob = __shfl_xor(best[pt][r], off, 16);
                float os = __shfl_xor(sec[pt][r], off, 16);
                int   oi = __shfl_xor(idx[pt][r], off, 16);
                bool take = (ob > best[pt][r]) ||
                            (ob == best[pt][r] && oi < idx[pt][r]);
                float nsec = fmaxf(fminf(ob, best[pt][r]),
                                   fmaxf(os, sec[pt][r]));
                best[pt][r] = take ? ob : best[pt][r];
                idx[pt][r]  = take ? oi : idx[pt][r];
                sec[pt][r]  = nsec;
            }
    }
    if ((lane & 15) == 0) {
        const int gq = lane >> 4;
        #pragma unroll
        for (int pt = 0; pt < 2; ++pt)
            #pragma unroll
            for (int r = 0; r < 4; ++r) {
                int pp = (w << 5) + (pt << 4) + (gq << 2) + r;
                int flag = (best[pt][r] - sec[pt][r] < MARGIN) ? 65536 : 0;
                bidxl[pp] = idx[pt][r] | flag;
            }
    }
    __syncthreads();

    // ---- build flagged list ----
    if (tid < 256) {
        int e = bidxl[tid];
        if (e & 65536) {
            int pos = atomicAdd(lcnt, 1);
            lflist[pos] = tid;
        }
    }
    __syncthreads();

    // ---- in-block exact rescan, one wave per flagged point --------------
    const float* dptr = ws + WS_DT;
    {
        const int nf = lcnt[0];
        for (int fi = w; fi < nf; fi += 8) {
            const int pp = lflist[fi];
            const float xv = x[(size_t)b * (DIMC * HWSZ)
                               + (size_t)lane * HWSZ + hwb + pp];
            float bb = -3.4e38f; int bj = 0;
            #pragma unroll 2
            for (int s = 0; s < 8; ++s) {
                const int j = (lane << 3) + s;
                const float4* row = (const float4*)(dptr + (size_t)j * DIMC);
                float a0 = 0.f, a1 = 0.f, a2 = 0.f, a3 = 0.f;
                #pragma unroll
                for (int c4 = 0; c4 < 16; ++c4) {
                    float4 r4 = row[c4];
                    a0 = fmaf(r4.x, __shfl(xv, 4 * c4 + 0), a0);
                    a1 = fmaf(r4.y, __shfl(xv, 4 * c4 + 1), a1);
                    a2 = fmaf(r4.z, __shfl(xv, 4 * c4 + 2), a2);
                    a3 = fmaf(r4.w, __shfl(xv, 4 * c4 + 3), a3);
                }
                float sc = ((a0 + a1) + (a2 + a3)) + lnrm[j];
                if (sc > bb) { bb = sc; bj = j; }
            }
            #pragma unroll
            for (int off = 1; off < 64; off <<= 1) {
                float ob = __shfl_xor(bb, off);
                int   oi = __shfl_xor(bj, off);
                bool take = (ob > bb) || (ob == bb && oi < bj);
                bb = take ? ob : bb;
                bj = take ? oi : bj;
            }
            if (lane == 0) bidxl[pp] = bj;
        }
    }
    __syncthreads();

    if (tid < 256) ((int*)ws)[WS_BIDX + nb + tid] = bidxl[tid] & 511;
}

// -------- K2b: gather/quantize/stats; all global stores post-barrier -----
__global__ __launch_bounds__(512, 1) void k_emit(
        const float* __restrict__ x, float* __restrict__ ws,
        float* __restrict__ out, int use_part) {
    extern __shared__ float lds[];
    float* esum  = lds;                 // 32768: esum_t [c][j]
    int*   lhist = (int*)(lds + 32768); // 512
    float* lred  = lds + 33280;         // 8

    const int tid = threadIdx.x;
    {
        float4 z = {0.f, 0.f, 0.f, 0.f};
        float4* e4 = (float4*)esum;
        #pragma unroll
        for (int k = 0; k < 16; ++k) e4[tid + 512 * k] = z;
        lhist[tid] = 0;
    }
    __syncthreads();

    const int n0 = blockIdx.x * 512 + tid;
    const int b = n0 >> 12, hw0 = n0 & 4095;
    const float* xp = x + (size_t)b * (DIMC * HWSZ) + hw0;
    float f0[DIMC];
    #pragma unroll
    for (int c = 0; c < DIMC; ++c) f0[c] = xp[c * HWSZ];

    const int bi0 = ((const int*)ws)[WS_BIDX + n0];
    atomicAdd(&lhist[bi0], 1);

    // esum scatter (LDS, banks spread by bidx)
    #pragma unroll
    for (int c = 0; c < DIMC; ++c) atomicAdd(&esum[c * NE + bi0], f0[c]);

    // q gather + diff partials (no stores yet)
    const float* dptr = ws + WS_DT;
    float ssum = 0.f;
    const float4* q40 = (const float4*)(dptr + (size_t)bi0 * DIMC);
    #pragma unroll
    for (int c4 = 0; c4 < 16; ++c4) {
        float4 qa = q40[c4];
        const int cb = 4 * c4;
        float d;
        d = qa.x - f0[cb + 0]; ssum = fmaf(d, d, ssum);
        d = qa.y - f0[cb + 1]; ssum = fmaf(d, d, ssum);
        d = qa.z - f0[cb + 2]; ssum = fmaf(d, d, ssum);
        d = qa.w - f0[cb + 3]; ssum = fmaf(d, d, ssum);
    }
    #pragma unroll
    for (int off = 32; off > 0; off >>= 1) ssum += __shfl_down(ssum, off);
    if ((tid & 63) == 0) lred[tid >> 6] = ssum;
    __syncthreads();

    // ---- post-barrier: all global stores (no trailing barrier/drain) ----
    if (use_part) {
        float* part = ws + WS_PART + (size_t)blockIdx.x * PART_STRIDE;
        float4* p4 = (float4*)part;
        const float4* e4 = (const float4*)esum;
        #pragma unroll
        for (int k = 0; k < 16; ++k) p4[tid + 512 * k] = e4[tid + 512 * k];
        part[32768 + tid] = (float)lhist[tid];
    } else {
        #pragma unroll
        for (int k = 0; k < 64; ++k)
            atomicAdd(&ws[WS_ESUM + tid + 512 * k], esum[tid + 512 * k]);
        atomicAdd(&ws[WS_COUNTS + tid], (float)lhist[tid]);
    }

    out[O2 + n0] = (float)bi0;
    float* o0 = out + O0 + (size_t)b * (DIMC * HWSZ) + hw0;
    #pragma unroll
    for (int c4 = 0; c4 < 16; ++c4) {
        float4 qa = q40[c4];        // re-gather (L2-hot)
        const int cb = 4 * c4;
        o0[(cb + 0) * HWSZ] = qa.x;
        o0[(cb + 1) * HWSZ] = qa.y;
        o0[(cb + 2) * HWSZ] = qa.z;
        o0[(cb + 3) * HWSZ] = qa.w;
    }

    if (tid == 0) {
        float t = 0.f;
        #pragma unroll
        for (int w2 = 0; w2 < 8; ++w2) t += lred[w2];
        atomicAdd(ws + WS_DIFF, t);
    }
}

// -------- K2d: parallel partial reduce (260 blocks, spread atomics) ------
__global__ void k_reduce(float* __restrict__ ws) {
    const int tid = threadIdx.x;
    const int gid = (blockIdx.x % 65) * 128 + tid;     // [0, 8320) float4 pos
    const int slice = blockIdx.x / 65;                  // [0, 4)
    const float4* src = (const float4*)(ws + WS_PART);
    float4 acc = {0.f, 0.f, 0.f, 0.f};
    const int p0 = slice * 64;
    #pragma unroll 4
    for (int p = p0; p < p0 + 64; ++p) {
        float4 v = src[(size_t)p * (PART_STRIDE / 4) + gid];
        acc.x += v.x; acc.y += v.y; acc.z += v.z; acc.w += v.w;
    }
    float* dst = ws + WS_ESUM + gid * 4;                // COUNTS follows ESUM
    atomicAdd(dst + 0, acc.x);
    atomicAdd(dst + 1, acc.y);
    atomicAdd(dst + 2, acc.z);
    atomicAdd(dst + 3, acc.w);
}

// -------- K3: finalize EMA buffers / outputs --------
__global__ void k_final(const float* __restrict__ ws,
                        const float* __restrict__ cluster_size,
                        const float* __restrict__ davg,
                        float* __restrict__ out) {
    __shared__ float red[16];
    __shared__ float nsh;
    const int j = threadIdx.x;

    float cnt = ws[WS_COUNTS + j];
    float ncs = DECAYF * cluster_size[j] + OMD * cnt;
    out[O3 + j] = ncs;

    float v = ncs;
    #pragma unroll
    for (int off = 32; off > 0; off >>= 1) v += __shfl_down(v, off);
    if ((j & 63) == 0) red[j >> 6] = v;
    __syncthreads();
    if (j == 0) {
        float t = 0.f;
        #pragma unroll
        for (int w = 0; w < 8; ++w) t += red[w];
        nsh = t;
    }
    __syncthreads();
    const float n = nsh;
    const float csj = (ncs + EPSF) / (n + NE * EPSF) * n;

    float asum = 0.f;
    #pragma unroll
    for (int c = 0; c < DIMC; ++c) {
        float es = ws[WS_ESUM + c * NE + j];
        float da = davg[c * NE + j];
        float nda = DECAYF * da + OMD * es;
        out[O4 + c * NE + j] = nda;
        float nd = nda / csj;
        out[O5 + c * NE + j] = nd;
        asum += fabsf(nd);
    }

    __syncthreads();
    #pragma unroll
    for (int off = 32; off > 0; off >>= 1) asum += __shfl_down(asum, off);
    if ((j & 63) == 0) red[j >> 6] = asum;
    __syncthreads();
    if (j == 0) {
        float t = 0.f;
        #pragma unroll
        for (int w = 0; w < 8; ++w) t += red[w];
        out[O6] = t / 32768.0f;
        out[O1] = ws[WS_DIFF] / 8388608.0f;
    }
}

extern "C" void kernel_launch(void* const* d_in, const int* in_sizes, int n_in,
                              void* d_out, int out_size, void* d_ws, size_t ws_size,
                              hipStream_t stream) {
    const float* x    = (const float*)d_in[0];
    const float* dict = (const float*)d_in[1];
    const float* csz  = (const float*)d_in[2];
    const float* davg = (const float*)d_in[3];
    float* out = (float*)d_out;
    float* ws  = (float*)d_ws;

    const int use_part = (ws_size >= WS_NEED_BYTES) ? 1 : 0;

    k_prep<<<512, 64, 0, stream>>>(dict, ws);

    const int score_lds = 25092 * 4;   // ~100.4 KB: dict pass + norms + staging
    hipFuncSetAttribute((const void*)k_score,
                        hipFuncAttributeMaxDynamicSharedMemorySize, score_lds);
    k_score<<<512, 512, score_lds, stream>>>(x, ws);

    const int emit_lds = 33288 * 4;
    hipFuncSetAttribute((const void*)k_emit,
                        hipFuncAttributeMaxDynamicSharedMemorySize, emit_lds);
    k_emit<<<NBLK, 512, emit_lds, stream>>>(x, ws, out, use_part);

    if (use_part) k_reduce<<<260, 128, 0, stream>>>(ws);

    k_final<<<1, 512, 0, stream>>>(ws, csz, davg, out);
}

// Round 18
// 147.555 us; speedup vs baseline: 1.1465x; 1.0019x over previous
//
#include <hip/hip_runtime.h>
#include <math.h>

#define DIMC 64
#define NE 512
#define HWSZ 4096              // 64*64
#define NPTS 131072
#define DECAYF 0.99f
#define OMD 0.01f
#define EPSF 1e-5f
#define MARGIN 1e-3f

// output offsets (floats) — out0 is [32,64,64,64] = 8388608 elements
#define O0 0
#define O1 8388608                 // diff scalar
#define O2 8388609                 // embed_ind [32,64,64]
#define O3 8519681                 // new_cluster_size [512]
#define O4 8520193                 // new_dictionary_avg [64,512]
#define O5 8552961                 // new_dictionary [64,512]
#define O6 8585729                 // mean_D scalar

// ws float-offset layout
#define WS_DIFF   0
#define WS_ESUM   64                       // [c][j] 64*512 f32 (reduced)
#define WS_COUNTS 32832                    // 512 f32 (contiguous after ESUM)
#define WS_DT     33344                    // [j][c] dictT f32, 32768
#define WS_NORM   66112                    // 512: -0.5*||d_j||^2
#define WS_DHI    66624                    // 512x64 bf16 (16384 floats)
#define WS_DLO    83008                    // 512x64 bf16
#define WS_BIDX   99392                    // NPTS ints (gap region)
#define WS_PART   246852                   // f32 partials: NBLK x 33280
#define PART_STRIDE 33280                  // 32768 esum + 512 counts
#define NBLK 256
#define WS_NEED_BYTES ((size_t)(WS_PART + (size_t)NBLK * PART_STRIDE) * 4)

typedef __attribute__((ext_vector_type(8))) short bf16x8;
typedef __attribute__((ext_vector_type(4))) float f32x4;

__device__ __forceinline__ unsigned bf16rne(float x) {
    unsigned u = __float_as_uint(x);
    return (u + 0x7FFFu + ((u >> 16) & 1u)) >> 16;
}

// -------- K1: dictT f32 + bf16 hi/lo + norms + zero accumulators --------
__global__ void k_prep(const float* __restrict__ dict, float* __restrict__ ws) {
    int j = blockIdx.x, c = threadIdx.x;
    float v = dict[c * NE + j];
    ws[WS_DT + j * DIMC + c] = v;
    unsigned h = bf16rne(v);
    float fh = __uint_as_float(h << 16);
    unsigned l = bf16rne(v - fh);
    ((unsigned short*)(ws + WS_DHI))[j * DIMC + c] = (unsigned short)h;
    ((unsigned short*)(ws + WS_DLO))[j * DIMC + c] = (unsigned short)l;
    ws[WS_ESUM + j * DIMC + c] = 0.f;      // reduce target (atomic-accumulated)
    if (c == 0) ws[WS_COUNTS + j] = 0.f;
    if (j == 0 && c == 0) ws[WS_DIFF] = 0.f;
    float s = v * v;
    #pragma unroll
    for (int off = 32; off > 0; off >>= 1) s += __shfl_down(s, off);
    if (c == 0) ws[WS_NORM + j] = -0.5f * s;
}

#define MFMA16(A, B, C) __builtin_amdgcn_mfma_f32_16x16x32_bf16(A, B, C, 0, 0, 0)

// -------- K2a: MFMA score, dict in LDS via FOUR-PASS staging -> bidx ------
// 512 blocks x 512 threads (8 waves); wave computes 32 points x 512 codes.
// Dict bf16 hi/lo staged 128 codes at a time (32 KB); LDS total 66 KB ->
// 2 blocks/CU co-resident (4 waves/SIMD).
__global__ __launch_bounds__(512, 1) void k_score(
        const float* __restrict__ x, float* __restrict__ ws) {
    extern __shared__ float lds[];
    uint4* ldh   = (uint4*)lds;            // [1024] pass dict hi (16 KB)
    uint4* ldl   = (uint4*)lds + 1024;     // [1024] pass dict lo (16 KB)
    float* lnrm  = lds + 8192;             // 512
    char*  stgB  = (char*)(lds + 8704);    // 32 KB x staging (hi then lo)
    int*   bidxl = (int*)(lds + 8704);     // overlay after frag loads: 256
    int*   lflist= (int*)(lds + 8704) + 256;
    int*   lcnt  = (int*)(lds + 8704) + 512;

    const int tid  = threadIdx.x;
    const int lane = tid & 63;
    const int w    = tid >> 6;

    const int nb  = blockIdx.x * 256;
    const int b   = nb >> 12;
    const int hwb = nb & 4095;

    const uint4* gdh = (const uint4*)(ws + WS_DHI);   // 4096 uint4 total
    const uint4* gdl = (const uint4*)(ws + WS_DLO);

    // ---- stage dict pass 0 (codes 0..127, hi+lo) + norms ----
    {
        #pragma unroll
        for (int k = 0; k < 2; ++k) {
            const int i = k * 512 + tid;           // [0, 1024)
            const int cl = i >> 3, ch = i & 7;     // code_local, chunk
            const int dp = cl * 8 + (ch ^ (cl & 7));
            ldh[dp] = gdh[i];
            ldl[dp] = gdl[i];
        }
        lnrm[tid] = ws[WS_NORM + tid];
    }

    // ---- staged x load: thread = (half h, point p); 32 c's each ----
    const int p = tid & 255, h = tid >> 8;
    const float* xp = x + (size_t)b * (DIMC * HWSZ) + (size_t)(32 * h) * HWSZ
                        + hwb + p;
    unsigned hiu[16], lou[16];
    #pragma unroll
    for (int i = 0; i < 16; ++i) {
        float v0 = xp[(2 * i) * HWSZ];
        float v1 = xp[(2 * i + 1) * HWSZ];
        unsigned h0 = bf16rne(v0), h1 = bf16rne(v1);
        float r0 = v0 - __uint_as_float(h0 << 16);
        float r1 = v1 - __uint_as_float(h1 << 16);
        hiu[i] = h0 | (h1 << 16);
        lou[i] = bf16rne(r0) | (bf16rne(r1) << 16);
    }
    const int swz = p & 7;
    #pragma unroll
    for (int k = 0; k < 4; ++k) {
        uint4 u = {hiu[4 * k], hiu[4 * k + 1], hiu[4 * k + 2], hiu[4 * k + 3]};
        *(uint4*)(stgB + p * 128 + (((4 * h + k) ^ swz) << 4)) = u;
    }
    __syncthreads();

    // ---- A-fragments hi (row = w*32 + pt*16 + (lane&15)) ----
    bf16x8 ahi[2][2], alo[2][2];
    #pragma unroll
    for (int pt = 0; pt < 2; ++pt) {
        const int row = (w << 5) + (pt << 4) + (lane & 15);
        #pragma unroll
        for (int kk = 0; kk < 2; ++kk) {
            const int ch = (lane >> 4) + (kk << 2);
            ahi[pt][kk] = __builtin_bit_cast(bf16x8,
                *(const uint4*)(stgB + row * 128 + ((ch ^ (row & 7)) << 4)));
        }
    }
    __syncthreads();

    // ---- stage x lo (same buffer), read lo frags ----
    #pragma unroll
    for (int k = 0; k < 4; ++k) {
        uint4 u = {lou[4 * k], lou[4 * k + 1], lou[4 * k + 2], lou[4 * k + 3]};
        *(uint4*)(stgB + p * 128 + (((4 * h + k) ^ swz) << 4)) = u;
    }
    __syncthreads();
    #pragma unroll
    for (int pt = 0; pt < 2; ++pt) {
        const int row = (w << 5) + (pt << 4) + (lane & 15);
        #pragma unroll
        for (int kk = 0; kk < 2; ++kk) {
            const int ch = (lane >> 4) + (kk << 2);
            alo[pt][kk] = __builtin_bit_cast(bf16x8,
                *(const uint4*)(stgB + row * 128 + ((ch ^ (row & 7)) << 4)));
        }
    }
    if (tid == 0) lcnt[0] = 0;
    __syncthreads();   // staging dead -> stgB reusable as bidxl/lflist

    // ---- MFMA sweep: 4 passes x 8 code-tiles; B from LDS ----
    const int col = lane & 15, g = lane >> 4;
    const int cswz = col & 7;
    const float* nl = lnrm + col;

    float best[2][4], sec[2][4];
    int   idx[2][4];
    #pragma unroll
    for (int pt = 0; pt < 2; ++pt)
        #pragma unroll
        for (int r = 0; r < 4; ++r) {
            best[pt][r] = -3.4e38f; sec[pt][r] = -3.4e38f; idx[pt][r] = 0;
        }

    for (int pass = 0; pass < 4; ++pass) {
        if (pass) {
            __syncthreads();   // all waves done with previous pass dict
            #pragma unroll
            for (int k = 0; k < 2; ++k) {
                const int i = k * 512 + tid;       // [0, 1024)
                const int cl = i >> 3, ch = i & 7;
                const int dp = cl * 8 + (ch ^ (cl & 7));
                ldh[dp] = gdh[pass * 1024 + i];
                ldl[dp] = gdl[pass * 1024 + i];
            }
            __syncthreads();
        }

        #pragma unroll 2
        for (int tt = 0; tt < 8; ++tt) {
            const int base = (tt << 7) + (col << 3);
            uint4 uh0 = ldh[base + (g ^ cswz)];
            uint4 uh1 = ldh[base + ((g + 4) ^ cswz)];
            uint4 ul0 = ldl[base + (g ^ cswz)];
            uint4 ul1 = ldl[base + ((g + 4) ^ cswz)];
            const int jt = (pass << 3) + tt;
            float nrm = nl[jt << 4];
            bf16x8 bh0 = __builtin_bit_cast(bf16x8, uh0);
            bf16x8 bh1 = __builtin_bit_cast(bf16x8, uh1);
            bf16x8 bl0 = __builtin_bit_cast(bf16x8, ul0);
            bf16x8 bl1 = __builtin_bit_cast(bf16x8, ul1);
            const int jc = (jt << 4) + col;
            #pragma unroll
            for (int pt = 0; pt < 2; ++pt) {
                f32x4 acc = {0.f, 0.f, 0.f, 0.f};
                acc = MFMA16(ahi[pt][0], bh0, acc);
                acc = MFMA16(ahi[pt][1], bh1, acc);
                acc = MFMA16(ahi[pt][0], bl0, acc);
                acc = MFMA16(ahi[pt][1], bl1, acc);
                acc = MFMA16(alo[pt][0], bh0, acc);
                acc = MFMA16(alo[pt][1], bh1, acc);
                acc = MFMA16(alo[pt][0], bl0, acc);
                acc = MFMA16(alo[pt][1], bl1, acc);
                #pragma unroll
                for (int r = 0; r < 4; ++r) {
                    float s = acc[r] + nrm;
                    bool gt = s > best[pt][r];
                    float ns = gt ? best[pt][r] : (s > sec[pt][r] ? s : sec[pt][r]);
                    best[pt][r] = gt ? s : best[pt][r];
                    idx[pt][r]  = gt ? jc : idx[pt][r];
                    sec[pt][r]  = ns;
                }
            }
        }
    }

    // ---- argmax reduce across 16-lane code groups ----
    #pragma unroll
    for (int off = 8; off > 0; off >>= 1) {
        #pragma unroll
        for (int pt = 0; pt < 2; ++pt)
            #pragma unroll
            for (int r = 0; r < 4; ++r) {
                float ob = __shfl_xor(best[pt][r], off, 16);
                float os = __shfl_xor(sec[pt][r], off, 16);
                int   oi = __shfl_xor(idx[pt][r], off, 16);
                bool take = (ob > best[pt][r]) ||
                            (ob == best[pt][r] && oi < idx[pt][r]);
                float nsec = fmaxf(fminf(ob, best[pt][r]),
                                   fmaxf(os, sec[pt][r]));
                best[pt][r] = take ? ob : best[pt][r];
                idx[pt][r]  = take ? oi : idx[pt][r];
                sec[pt][r]  = nsec;
            }
    }
    if ((lane & 15) == 0) {
        const int gq = lane >> 4;
        #pragma unroll
        for (int pt = 0; pt < 2; ++pt)
            #pragma unroll
            for (int r = 0; r < 4; ++r) {
                int pp = (w << 5) + (pt << 4) + (gq << 2) + r;
                int flag = (best[pt][r] - sec[pt][r] < MARGIN) ? 65536 : 0;
                bidxl[pp] = idx[pt][r] | flag;
            }
    }
    __syncthreads();

    // ---- build flagged list ----
    if (tid < 256) {
        int e = bidxl[tid];
        if (e & 65536) {
            int pos = atomicAdd(lcnt, 1);
            lflist[pos] = tid;
        }
    }
    __syncthreads();

    // ---- in-block exact rescan, one wave per flagged point --------------
    const float* dptr = ws + WS_DT;
    {
        const int nf = lcnt[0];
        for (int fi = w; fi < nf; fi += 8) {
            const int pp = lflist[fi];
            const float xv = x[(size_t)b * (DIMC * HWSZ)
                               + (size_t)lane * HWSZ + hwb + pp];
            float bb = -3.4e38f; int bj = 0;
            #pragma unroll 2
            for (int s = 0; s < 8; ++s) {
                const int j = (lane << 3) + s;
                const float4* row = (const float4*)(dptr + (size_t)j * DIMC);
                float a0 = 0.f, a1 = 0.f, a2 = 0.f, a3 = 0.f;
                #pragma unroll
                for (int c4 = 0; c4 < 16; ++c4) {
                    float4 r4 = row[c4];
                    a0 = fmaf(r4.x, __shfl(xv, 4 * c4 + 0), a0);
                    a1 = fmaf(r4.y, __shfl(xv, 4 * c4 + 1), a1);
                    a2 = fmaf(r4.z, __shfl(xv, 4 * c4 + 2), a2);
                    a3 = fmaf(r4.w, __shfl(xv, 4 * c4 + 3), a3);
                }
                float sc = ((a0 + a1) + (a2 + a3)) + lnrm[j];
                if (sc > bb) { bb = sc; bj = j; }
            }
            #pragma unroll
            for (int off = 1; off < 64; off <<= 1) {
                float ob = __shfl_xor(bb, off);
                int   oi = __shfl_xor(bj, off);
                bool take = (ob > bb) || (ob == bb && oi < bj);
                bb = take ? ob : bb;
                bj = take ? oi : bj;
            }
            if (lane == 0) bidxl[pp] = bj;
        }
    }
    __syncthreads();

    if (tid < 256) ((int*)ws)[WS_BIDX + nb + tid] = bidxl[tid] & 511;
}

// -------- K2b: gather/quantize/stats; all global stores post-barrier -----
__global__ __launch_bounds__(512, 1) void k_emit(
        const float* __restrict__ x, float* __restrict__ ws,
        float* __restrict__ out, int use_part) {
    extern __shared__ float lds[];
    float* esum  = lds;                 // 32768: esum_t [c][j]
    int*   lhist = (int*)(lds + 32768); // 512
    float* lred  = lds + 33280;         // 8

    const int tid = threadIdx.x;
    {
        float4 z = {0.f, 0.f, 0.f, 0.f};
        float4* e4 = (float4*)esum;
        #pragma unroll
        for (int k = 0; k < 16; ++k) e4[tid + 512 * k] = z;
        lhist[tid] = 0;
    }
    __syncthreads();

    const int n0 = blockIdx.x * 512 + tid;
    const int b = n0 >> 12, hw0 = n0 & 4095;
    const float* xp = x + (size_t)b * (DIMC * HWSZ) + hw0;
    float f0[DIMC];
    #pragma unroll
    for (int c = 0; c < DIMC; ++c) f0[c] = xp[c * HWSZ];

    const int bi0 = ((const int*)ws)[WS_BIDX + n0];
    atomicAdd(&lhist[bi0], 1);

    // esum scatter (LDS, banks spread by bidx)
    #pragma unroll
    for (int c = 0; c < DIMC; ++c) atomicAdd(&esum[c * NE + bi0], f0[c]);

    // q gather + diff partials (no stores yet)
    const float* dptr = ws + WS_DT;
    float ssum = 0.f;
    const float4* q40 = (const float4*)(dptr + (size_t)bi0 * DIMC);
    #pragma unroll
    for (int c4 = 0; c4 < 16; ++c4) {
        float4 qa = q40[c4];
        const int cb = 4 * c4;
        float d;
        d = qa.x - f0[cb + 0]; ssum = fmaf(d, d, ssum);
        d = qa.y - f0[cb + 1]; ssum = fmaf(d, d, ssum);
        d = qa.z - f0[cb + 2]; ssum = fmaf(d, d, ssum);
        d = qa.w - f0[cb + 3]; ssum = fmaf(d, d, ssum);
    }
    #pragma unroll
    for (int off = 32; off > 0; off >>= 1) ssum += __shfl_down(ssum, off);
    if ((tid & 63) == 0) lred[tid >> 6] = ssum;
    __syncthreads();

    // ---- post-barrier: all global stores (no trailing barrier/drain) ----
    if (use_part) {
        float* part = ws + WS_PART + (size_t)blockIdx.x * PART_STRIDE;
        float4* p4 = (float4*)part;
        const float4* e4 = (const float4*)esum;
        #pragma unroll
        for (int k = 0; k < 16; ++k) p4[tid + 512 * k] = e4[tid + 512 * k];
        part[32768 + tid] = (float)lhist[tid];
    } else {
        #pragma unroll
        for (int k = 0; k < 64; ++k)
            atomicAdd(&ws[WS_ESUM + tid + 512 * k], esum[tid + 512 * k]);
        atomicAdd(&ws[WS_COUNTS + tid], (float)lhist[tid]);
    }

    out[O2 + n0] = (float)bi0;
    float* o0 = out + O0 + (size_t)b * (DIMC * HWSZ) + hw0;
    #pragma unroll
    for (int c4 = 0; c4 < 16; ++c4) {
        float4 qa = q40[c4];        // re-gather (L2-hot)
        const int cb = 4 * c4;
        o0[(cb + 0) * HWSZ] = qa.x;
        o0[(cb + 1) * HWSZ] = qa.y;
        o0[(cb + 2) * HWSZ] = qa.z;
        o0[(cb + 3) * HWSZ] = qa.w;
    }

    if (tid == 0) {
        float t = 0.f;
        #pragma unroll
        for (int w2 = 0; w2 < 8; ++w2) t += lred[w2];
        atomicAdd(ws + WS_DIFF, t);
    }
}

// -------- K2d: parallel partial reduce (260 blocks, spread atomics) ------
__global__ void k_reduce(float* __restrict__ ws) {
    const int tid = threadIdx.x;
    const int gid = (blockIdx.x % 65) * 128 + tid;     // [0, 8320) float4 pos
    const int slice = blockIdx.x / 65;                  // [0, 4)
    const float4* src = (const float4*)(ws + WS_PART);
    float4 acc = {0.f, 0.f, 0.f, 0.f};
    const int p0 = slice * 64;
    #pragma unroll 4
    for (int p = p0; p < p0 + 64; ++p) {
        float4 v = src[(size_t)p * (PART_STRIDE / 4) + gid];
        acc.x += v.x; acc.y += v.y; acc.z += v.z; acc.w += v.w;
    }
    float* dst = ws + WS_ESUM + gid * 4;                // COUNTS follows ESUM
    atomicAdd(dst + 0, acc.x);
    atomicAdd(dst + 1, acc.y);
    atomicAdd(dst + 2, acc.z);
    atomicAdd(dst + 3, acc.w);
}

// -------- K3: finalize EMA buffers / outputs --------
__global__ void k_final(const float* __restrict__ ws,
                        const float* __restrict__ cluster_size,
                        const float* __restrict__ davg,
                        float* __restrict__ out) {
    __shared__ float red[16];
    __shared__ float nsh;
    const int j = threadIdx.x;

    float cnt = ws[WS_COUNTS + j];
    float ncs = DECAYF * cluster_size[j] + OMD * cnt;
    out[O3 + j] = ncs;

    float v = ncs;
    #pragma unroll
    for (int off = 32; off > 0; off >>= 1) v += __shfl_down(v, off);
    if ((j & 63) == 0) red[j >> 6] = v;
    __syncthreads();
    if (j == 0) {
        float t = 0.f;
        #pragma unroll
        for (int w = 0; w < 8; ++w) t += red[w];
        nsh = t;
    }
    __syncthreads();
    const float n = nsh;
    const float csj = (ncs + EPSF) / (n + NE * EPSF) * n;

    float asum = 0.f;
    #pragma unroll
    for (int c = 0; c < DIMC; ++c) {
        float es = ws[WS_ESUM + c * NE + j];
        float da = davg[c * NE + j];
        float nda = DECAYF * da + OMD * es;
        out[O4 + c * NE + j] = nda;
        float nd = nda / csj;
        out[O5 + c * NE + j] = nd;
        asum += fabsf(nd);
    }

    __syncthreads();
    #pragma unroll
    for (int off = 32; off > 0; off >>= 1) asum += __shfl_down(asum, off);
    if ((j & 63) == 0) red[j >> 6] = asum;
    __syncthreads();
    if (j == 0) {
        float t = 0.f;
        #pragma unroll
        for (int w = 0; w < 8; ++w) t += red[w];
        out[O6] = t / 32768.0f;
        out[O1] = ws[WS_DIFF] / 8388608.0f;
    }
}

extern "C" void kernel_launch(void* const* d_in, const int* in_sizes, int n_in,
                              void* d_out, int out_size, void* d_ws, size_t ws_size,
                              hipStream_t stream) {
    const float* x    = (const float*)d_in[0];
    const float* dict = (const float*)d_in[1];
    const float* csz  = (const float*)d_in[2];
    const float* davg = (const float*)d_in[3];
    float* out = (float*)d_out;
    float* ws  = (float*)d_ws;

    const int use_part = (ws_size >= WS_NEED_BYTES) ? 1 : 0;

    k_prep<<<512, 64, 0, stream>>>(dict, ws);

    const int score_lds = 16896 * 4;   // 66 KB: dict pass (32K) + norms + staging
    hipFuncSetAttribute((const void*)k_score,
                        hipFuncAttributeMaxDynamicSharedMemorySize, score_lds);
    k_score<<<512, 512, score_lds, stream>>>(x, ws);

    const int emit_lds = 33288 * 4;
    hipFuncSetAttribute((const void*)k_emit,
                        hipFuncAttributeMaxDynamicSharedMemorySize, emit_lds);
    k_emit<<<NBLK, 512, emit_lds, stream>>>(x, ws, out, use_part);

    if (use_part) k_reduce<<<260, 128, 0, stream>>>(ws);

    k_final<<<1, 512, 0, stream>>>(ws, csz, davg, out);
}